// Round 1
// baseline (615.560 us; speedup 1.0000x reference)
//
#include <hip/hip_runtime.h>

// LRU-style linear recurrence, fully fused.
// Shapes: NY=64, NU=32, NH=512 (NH2=256 complex pairs), T=512, BATCH=256.
// One block per batch element (256 blocks -> 1 block/CU), 256 threads (4 waves).
// Thread j owns complex pair j: state (xr, xi) in registers.
// Wave w / lane o computes Y-partial over hidden chunk [w*128, w*128+128).

constexpr int NY  = 64;
constexpr int NU  = 32;
constexpr int NH  = 512;
constexpr int NH2 = 256;
constexpr int TT  = 512;
constexpr int BB  = 256;

__global__ __launch_bounds__(256, 1)
void lru_fused_kernel(const float* __restrict__ y0,     // [BB][NY]
                      const float* __restrict__ U,      // [TT][BB][NU]
                      const float* __restrict__ lmr,    // [NH2]
                      const float* __restrict__ lmi,    // [NH2]
                      const float* __restrict__ B,      // [NH][NU]
                      const float* __restrict__ Wy2x,   // [NH][NY]
                      const float* __restrict__ by2x,   // [NH]
                      const float* __restrict__ Wx2y,   // [NY][NH]
                      const float* __restrict__ bx2y,   // [NY]
                      float* __restrict__ Y)            // [TT+1][BB][NY]
{
    const int b   = blockIdx.x;
    const int tid = threadIdx.x;
    const int w   = tid >> 6;   // wave id 0..3
    const int o   = tid & 63;   // lane = output index

    __shared__ float xs[NH];            // full state vector, rebuilt per step
    __shared__ float ps[4][NY];         // per-wave Y partials
    __shared__ float us[2][64 * NU];    // double-buffered 64-step U chunks (16 KB)
    __shared__ float y0s[NY];

    // ---- one-time register loads ----
    float Br[NU], Bi[NU];
#pragma unroll
    for (int k = 0; k < NU; ++k) {
        Br[k] = B[tid * NU + k];
        Bi[k] = B[(NH2 + tid) * NU + k];
    }
    float Wreg[128];
#pragma unroll
    for (int k = 0; k < 128; ++k)
        Wreg[k] = Wx2y[o * NH + (w << 7) + k];
    const float lr   = lmr[tid];
    const float li   = lmi[tid];
    const float bias = bx2y[o];

    if (tid < NY) y0s[tid] = y0[b * NY + tid];

    // ---- stage U chunk 0 (t = 0..63) into us[0] ----
    const float4* Ug   = reinterpret_cast<const float4*>(U);
    float4*       us40 = reinterpret_cast<float4*>(us[0]);
    float4*       us41 = reinterpret_cast<float4*>(us[1]);
    {
        const int i0 = tid, i1 = tid + 256;          // 512 vec4 per chunk
        us40[i0] = Ug[((i0 >> 3) * BB + b) * 8 + (i0 & 7)];
        us40[i1] = Ug[((i1 >> 3) * BB + b) * 8 + (i1 & 7)];
    }
    __syncthreads();

    // ---- x0 = y0 @ Wy2x^T + by2x ----
    float xr, xi;
    {
        const float* wr = &Wy2x[tid * NY];
        const float* wi = &Wy2x[(NH2 + tid) * NY];
        float a0 = 0, a1 = 0, a2 = 0, a3 = 0;
        float c0 = 0, c1 = 0, c2 = 0, c3 = 0;
#pragma unroll
        for (int y = 0; y < NY; y += 4) {
            a0 += wr[y + 0] * y0s[y + 0];
            a1 += wr[y + 1] * y0s[y + 1];
            a2 += wr[y + 2] * y0s[y + 2];
            a3 += wr[y + 3] * y0s[y + 3];
            c0 += wi[y + 0] * y0s[y + 0];
            c1 += wi[y + 1] * y0s[y + 1];
            c2 += wi[y + 2] * y0s[y + 2];
            c3 += wi[y + 3] * y0s[y + 3];
        }
        xr = by2x[tid]       + (a0 + a1) + (a2 + a3);
        xi = by2x[NH2 + tid] + (c0 + c1) + (c2 + c3);
    }

    float4 pf0, pf1;      // prefetch registers for next U chunk
    float  ybuf[8];       // wave-0 store buffer (amortize store drain)

    for (int s = 0; s <= TT; ++s) {
        if (s >= 1) {
            const int t  = s - 1;
            const int tc = t & 63;
            const int c  = t >> 6;

            // bu = B[pair] . U[t]  (U broadcast from LDS, uniform address)
            const float* uu = &us[c & 1][tc * NU];
            float r0 = 0, r1 = 0, r2 = 0, r3 = 0;
            float i0 = 0, i1 = 0, i2 = 0, i3 = 0;
#pragma unroll
            for (int k = 0; k < NU; k += 4) {
                r0 += Br[k + 0] * uu[k + 0];
                r1 += Br[k + 1] * uu[k + 1];
                r2 += Br[k + 2] * uu[k + 2];
                r3 += Br[k + 3] * uu[k + 3];
                i0 += Bi[k + 0] * uu[k + 0];
                i1 += Bi[k + 1] * uu[k + 1];
                i2 += Bi[k + 2] * uu[k + 2];
                i3 += Bi[k + 3] * uu[k + 3];
            }
            const float bur = (r0 + r1) + (r2 + r3);
            const float bui = (i0 + i1) + (i2 + i3);

            // complex diagonal state update
            const float nr = lr * xr - li * xi + bur;
            const float ni = li * xr + lr * xi + bui;
            xr = nr;
            xi = ni;

            // U chunk prefetch: issue loads at chunk start, commit to LDS
            // mid-chunk (32 iters of slack -> no vmcnt stall at the ds_write).
            if (tc == 0 && c < 7) {
                const int i0v = tid, i1v = tid + 256;
                const int t0g = ((c + 1) << 6) + (i0v >> 3);
                const int t1g = ((c + 1) << 6) + (i1v >> 3);
                pf0 = Ug[(t0g * BB + b) * 8 + (i0v & 7)];
                pf1 = Ug[(t1g * BB + b) * 8 + (i1v & 7)];
            }
            if (tc == 32 && c < 7) {
                float4* dst = ((c + 1) & 1) ? us41 : us40;
                dst[tid]       = pf0;
                dst[tid + 256] = pf1;
            }
        }

        // publish state
        xs[tid]       = xr;
        xs[NH2 + tid] = xi;
        __syncthreads();   // A: state + U chunk visible

        // Y partial: lane o over hidden chunk [w*128, w*128+128)
        const float* xw = &xs[w << 7];
        float p0 = 0, p1 = 0, p2 = 0, p3 = 0;
#pragma unroll
        for (int k = 0; k < 128; k += 4) {
            p0 += Wreg[k + 0] * xw[k + 0];
            p1 += Wreg[k + 1] * xw[k + 1];
            p2 += Wreg[k + 2] * xw[k + 2];
            p3 += Wreg[k + 3] * xw[k + 3];
        }
        ps[w][o] = (p0 + p1) + (p2 + p3);
        __syncthreads();   // B: partials visible

        if (w == 0) {
            ybuf[s & 7] = ps[0][o] + ps[1][o] + ps[2][o] + ps[3][o] + bias;
            if ((s & 7) == 7 || s == TT) {
                const int s0 = s & ~7;
#pragma unroll
                for (int q = 0; q < 8; ++q)
                    if (s0 + q <= s)
                        Y[((s0 + q) * BB + b) * NY + o] = ybuf[q];
            }
        }
    }
}

extern "C" void kernel_launch(void* const* d_in, const int* in_sizes, int n_in,
                              void* d_out, int out_size, void* d_ws, size_t ws_size,
                              hipStream_t stream) {
    const float* y0   = (const float*)d_in[0];
    const float* U    = (const float*)d_in[1];
    const float* lmr  = (const float*)d_in[2];
    const float* lmi  = (const float*)d_in[3];
    const float* B    = (const float*)d_in[4];
    const float* Wy2x = (const float*)d_in[5];
    const float* by2x = (const float*)d_in[6];
    const float* Wx2y = (const float*)d_in[7];
    const float* bx2y = (const float*)d_in[8];
    float* Y = (float*)d_out;

    lru_fused_kernel<<<dim3(BB), dim3(256), 0, stream>>>(
        y0, U, lmr, lmi, B, Wy2x, by2x, Wx2y, bx2y, Y);
}